// Round 1
// baseline (202.720 us; speedup 1.0000x reference)
//
#include <hip/hip_runtime.h>
#include <hip/hip_bf16.h>

#define BN    4112            // sequence length
#define NKR   4160            // padded key rows: 4048 main + 48 zero-pad + 64 mem
#define BNP   4160            // V^T col stride (= NKR)
#define BB    2
#define HH    8
#define NIMG_ 4096
#define NMAIN 4048
#define MROWS 8224            // BB*BN
// (1/sqrt(32)) * log2(e): folded into Q so attention uses raw v_exp_f32 (2^x)
#define QSCALE 0.25505402f

typedef __attribute__((ext_vector_type(8))) short short8;   // 8 bf16 (4 VGPRs)
typedef __attribute__((ext_vector_type(4))) float f32x4;

__device__ __forceinline__ unsigned short f2bs(float x) { return __bfloat16_as_ushort(__float2bfloat16(x)); }
__device__ __forceinline__ unsigned pkbf(float a, float b) {
    __hip_bfloat162 h = __float22bfloat162_rn(make_float2(a, b));   // v_cvt_pk_bf16_f32
    unsigned u; __builtin_memcpy(&u, &h, 4); return u;
}
__device__ __forceinline__ float fexp2(float x) {
#if __has_builtin(__builtin_amdgcn_exp2f)
    return __builtin_amdgcn_exp2f(x);
#else
    return exp2f(x);
#endif
}

// ---------------- fused QKV projection (one launch) ---------------- (unchanged)
__global__ __launch_bounds__(256)
void qkv_mfma(const float* __restrict__ Aq, const float* __restrict__ Ak, const float* __restrict__ Av,
              const float* __restrict__ Wq, const float* __restrict__ Wk, const float* __restrict__ Wv,
              const float* __restrict__ bq, const float* __restrict__ bk, const float* __restrict__ bv,
              short* __restrict__ Qr, short* __restrict__ Kr, short* __restrict__ Vt,
              const float* __restrict__ fimg, const float* __restrict__ ftxt)
{
    __shared__ __align__(16) short Ws[2][64][72];
    __shared__ __align__(16) short Ds[2][64][72];

    const int mode = blockIdx.z;
    const float* A    = (mode == 0) ? Aq : (mode == 1) ? Ak : Av;
    const float* W    = (mode == 0) ? Wq : (mode == 1) ? Wk : Wv;
    const float* bias = (mode == 0) ? bq : (mode == 1) ? bk : bv;

    const int t    = threadIdx.x;
    const int wave = t >> 6, lane = t & 63, q16 = lane & 15, quad = lane >> 4;
    const int f0 = blockIdx.x * 64;
    const int m0 = blockIdx.y * 64;
    const int sr = t >> 2, sc = (t & 3) * 16;
    const int arow = m0 + sr;
    const bool aval = arow < MROWS;
    const float* wp = W + (size_t)(f0 + sr) * 256 + sc;
    const float* ap = A + (size_t)(aval ? arow : 0) * 256 + sc;

    f32x4 acc[4] = {{0,0,0,0},{0,0,0,0},{0,0,0,0},{0,0,0,0}};

    uint4 wr0, wr1, dr0, dr1;
    {
        float4 a0 = *(const float4*)(wp),     a1 = *(const float4*)(wp + 4);
        float4 a2 = *(const float4*)(wp + 8), a3 = *(const float4*)(wp + 12);
        wr0 = uint4{pkbf(a0.x,a0.y), pkbf(a0.z,a0.w), pkbf(a1.x,a1.y), pkbf(a1.z,a1.w)};
        wr1 = uint4{pkbf(a2.x,a2.y), pkbf(a2.z,a2.w), pkbf(a3.x,a3.y), pkbf(a3.z,a3.w)};
        a0 = *(const float4*)(ap);     a1 = *(const float4*)(ap + 4);
        a2 = *(const float4*)(ap + 8); a3 = *(const float4*)(ap + 12);
        dr0 = uint4{pkbf(a0.x,a0.y), pkbf(a0.z,a0.w), pkbf(a1.x,a1.y), pkbf(a1.z,a1.w)};
        dr1 = uint4{pkbf(a2.x,a2.y), pkbf(a2.z,a2.w), pkbf(a3.x,a3.y), pkbf(a3.z,a3.w)};
    }
    *(uint4*)&Ws[0][sr][sc] = wr0; *(uint4*)&Ws[0][sr][sc + 8] = wr1;
    *(uint4*)&Ds[0][sr][sc] = dr0; *(uint4*)&Ds[0][sr][sc + 8] = dr1;
    __syncthreads();

    #pragma unroll
    for (int ki = 0; ki < 4; ++ki) {
        const int buf = ki & 1;
        if (ki < 3) {
            const int k1 = (ki + 1) * 64;
            float4 a0 = *(const float4*)(wp + k1),     a1 = *(const float4*)(wp + k1 + 4);
            float4 a2 = *(const float4*)(wp + k1 + 8), a3 = *(const float4*)(wp + k1 + 12);
            wr0 = uint4{pkbf(a0.x,a0.y), pkbf(a0.z,a0.w), pkbf(a1.x,a1.y), pkbf(a1.z,a1.w)};
            wr1 = uint4{pkbf(a2.x,a2.y), pkbf(a2.z,a2.w), pkbf(a3.x,a3.y), pkbf(a3.z,a3.w)};
            a0 = *(const float4*)(ap + k1);     a1 = *(const float4*)(ap + k1 + 4);
            a2 = *(const float4*)(ap + k1 + 8); a3 = *(const float4*)(ap + k1 + 12);
            dr0 = uint4{pkbf(a0.x,a0.y), pkbf(a0.z,a0.w), pkbf(a1.x,a1.y), pkbf(a1.z,a1.w)};
            dr1 = uint4{pkbf(a2.x,a2.y), pkbf(a2.z,a2.w), pkbf(a3.x,a3.y), pkbf(a3.z,a3.w)};
        }
        #pragma unroll
        for (int ks = 0; ks < 2; ++ks) {
            const short8 af = *(const short8*)&Ws[buf][wave * 16 + q16][ks * 32 + quad * 8];
            #pragma unroll
            for (int ct = 0; ct < 4; ++ct) {
                const short8 bf = *(const short8*)&Ds[buf][ct * 16 + q16][ks * 32 + quad * 8];
                acc[ct] = __builtin_amdgcn_mfma_f32_16x16x32_bf16(af, bf, acc[ct], 0, 0, 0);
            }
        }
        if (ki < 3) {
            *(uint4*)&Ws[buf ^ 1][sr][sc] = wr0; *(uint4*)&Ws[buf ^ 1][sr][sc + 8] = wr1;
            *(uint4*)&Ds[buf ^ 1][sr][sc] = dr0; *(uint4*)&Ds[buf ^ 1][sr][sc + 8] = dr1;
            __syncthreads();
        }
    }

    const int fbase = f0 + wave * 16 + quad * 4;
    const float4 bb = *(const float4*)(bias + fbase);
    float vs[4][4];
    #pragma unroll
    for (int ct = 0; ct < 4; ++ct) {
        int n = m0 + ct * 16 + q16;
        float v0 = acc[ct][0] + bb.x, v1 = acc[ct][1] + bb.y;
        float v2 = acc[ct][2] + bb.z, v3 = acc[ct][3] + bb.w;
        int b  = (n >= BN) ? 1 : 0;
        int nb = n - b * BN;
        if (mode < 2) {
            int j0 = (fbase & 31) >> 1;
            const float* fr = (nb < NIMG_) ? (fimg + ((size_t)nb * 16 + j0) * 2)
                                           : (ftxt + ((size_t)(nb - NIMG_) * 16 + j0) * 2);
            float4 cs = *(const float4*)fr;
            float r0 = v0 * cs.x - v1 * cs.y, i0 = v0 * cs.y + v1 * cs.x;
            float r1 = v2 * cs.z - v3 * cs.w, i1 = v2 * cs.w + v3 * cs.z;
            v0 = r0; v1 = i0; v2 = r1; v3 = i1;
        }
        if (mode == 2) {
            vs[ct][0] = v0; vs[ct][1] = v1; vs[ct][2] = v2; vs[ct][3] = v3;
            continue;
        }
        if (n >= MROWS) continue;
        const int h = (fbase >> 5) & 7, hd = fbase & 31;
        if (mode == 0) {
            unsigned short* op = (unsigned short*)Qr + (((size_t)(b * HH + h) * BN + nb) * 32 + hd);
            *(uint2*)op = uint2{pkbf(v0 * QSCALE, v1 * QSCALE), pkbf(v2 * QSCALE, v3 * QSCALE)};
        } else {
            int nk = nb + ((nb >= NMAIN) ? 48 : 0);
            unsigned short* op = (unsigned short*)Kr + (((size_t)(b * HH + h) * NKR + nk) * 32 + hd);
            *(uint2*)op = uint2{pkbf(v0, v1), pkbf(v2, v3)};
        }
    }

    if (mode == 2) {
        short (*Tr)[72] = Ds[0];
        const int fl = wave * 16 + quad * 4;
        #pragma unroll
        for (int ct = 0; ct < 4; ++ct) {
            const int nl = ct * 16 + q16;
            Tr[fl + 0][nl] = (short)f2bs(vs[ct][0]);
            Tr[fl + 1][nl] = (short)f2bs(vs[ct][1]);
            Tr[fl + 2][nl] = (short)f2bs(vs[ct][2]);
            Tr[fl + 3][nl] = (short)f2bs(vs[ct][3]);
        }
        __syncthreads();
        const int h0 = (f0 >> 5) & 7;
        #pragma unroll
        for (int ii = 0; ii < 2; ++ii) {
            const int r  = ii * 32 + (t >> 3);
            const int c8 = (t & 7) * 8;
            const int ng = m0 + c8;
            if (ng < MROWS) {
                uint4 val = *(const uint4*)&Tr[r][c8];
                int b  = (ng >= BN) ? 1 : 0;
                int nb = ng - b * BN;
                int nk = nb + ((nb >= NMAIN) ? 48 : 0);
                int h  = h0 + (r >> 5), hd = r & 31;
                unsigned short* op = (unsigned short*)Vt + ((size_t)(b * HH + h) * 32 + hd) * BNP + nk;
                *(uint4*)op = val;
            }
        }
    }

    if (blockIdx.x == 0 && blockIdx.y < 16 && t < 192) {
        const int bh = blockIdx.y;
        if (mode == 1) {
            short* base = Kr + (size_t)bh * NKR * 32 + (size_t)NMAIN * 32;
            *(uint4*)(base + t * 8) = uint4{0u, 0u, 0u, 0u};
        } else if (mode == 2) {
            short* base = Vt + (size_t)bh * 32 * BNP + (size_t)(t / 6) * BNP + NMAIN + (t % 6) * 8;
            *(uint4*)base = uint4{0u, 0u, 0u, 0u};
        }
    }
}

// ---------------- MFMA flash attention: in-register P + intra-block key-split ----------------
// 512 thr = 8 waves = 2 groups x 4 waves. Both groups cover the SAME 64 queries; group 0
// handles key-tiles 0..31, group 1 tiles 32..64 (incl. 48 zero-pads in tile 63 and the mem
// segment tile 64). Each group: own double-buffered K/V LDS, register prefetch, in-register
// P via permuted-k PV (k-slot (quad,j) -> key quad*4+(j&3)+16*(j>>2)). One barrier/iter.
// NEW (this round): Vs is stored in k-slot-permuted column order (c' = quad*8 + hi*4 + j
// holds key hi*16 + quad*4 + j per 32-key half). The permutation is applied on the GLOBAL
// source address at staging (two 8B loads -> one b128 LDS write, LDS stays linear), so the
// PV fragment read is ONE conflict-free ds_read_b128 instead of 16 bank-conflicted b32s.
// Merge: group 0 partial (O, L) -> LDS -> group 1 normalizes, adds mem softmax, stores.
__global__ __launch_bounds__(512, 8)
void attn_mfma(const short* __restrict__ Qr, const short* __restrict__ Kr,
               const short* __restrict__ Vt, unsigned short* __restrict__ AO)
{
    __shared__ __align__(16) short Ks[2][2][64][40];   // [group][buf] 20480 B
    __shared__ __align__(16) short Vs[2][2][32][72];   // [group][buf] 18432 B

    const int t    = threadIdx.x;
    const int wave = t >> 6, lane = t & 63, q16 = lane & 15, quad = lane >> 4;
    const int grp  = wave >> 2, w4 = wave & 3;
    const int bh = blockIdx.y;
    const int q  = blockIdx.x * 64 + w4 * 16 + q16;
    const int qc = (q < BN) ? q : (BN - 1);
    const short8 qf = *(const short8*)(Qr + ((size_t)bh * BN + qc) * 32 + quad * 8);

    f32x4 oA0 = {0,0,0,0}, oA1 = {0,0,0,0}, oB0 = {0,0,0,0}, oB1 = {0,0,0,0};
    float LA = 0.f, LB = 0.f;

    const int tg = t & 255;                 // group-local thread id
    const int kr = tg >> 2, kc = tg & 3;
    const int vr = tg >> 3, vc = tg & 7;
    // group g starts at tile 32*g: +65536 shorts in Kr rows, +2048 cols in Vt
    const short* kg = Kr + (size_t)bh * NKR * 32 + (size_t)grp * 65536 + (size_t)kr * 32 + kc * 8;
    // V staging source: inverse k-slot permutation applied on the global address.
    // Thread (vr, vc) fills Vs[vr][vc*8 .. vc*8+7]; quad = vc&3, half = vc>>2:
    //   slots 0..3 <- keys half*32 + quad*4 + j, slots 4..7 <- keys half*32 + 16 + quad*4 + j
    const short* vg = Vt + (size_t)bh * 32 * BNP + (size_t)vr * BNP + grp * 2048
                         + (vc >> 2) * 32 + (vc & 3) * 4;
    const int ntiles = 32 + grp;            // group 0: 32 tiles, group 1: 33 (incl. mem)

    auto tile = [&](int buf, f32x4& o0, f32x4& o1, float& L) {
        float lsum = 0.f;
        #pragma unroll
        for (int g = 0; g < 2; ++g) {
            const short8 kf0 = *(const short8*)&Ks[grp][buf][(2*g)     * 16 + q16][quad * 8];
            const short8 kf1 = *(const short8*)&Ks[grp][buf][(2*g + 1) * 16 + q16][quad * 8];
            f32x4 z = {0,0,0,0};
            f32x4 s0 = __builtin_amdgcn_mfma_f32_16x16x32_bf16(kf0, qf, z, 0, 0, 0);
            f32x4 s1 = __builtin_amdgcn_mfma_f32_16x16x32_bf16(kf1, qf, z, 0, 0, 0);
            float p0 = fexp2(s0[0]), p1 = fexp2(s0[1]), p2 = fexp2(s0[2]), p3 = fexp2(s0[3]);
            float p4 = fexp2(s1[0]), p5 = fexp2(s1[1]), p6 = fexp2(s1[2]), p7 = fexp2(s1[3]);
            lsum += ((p0 + p1) + (p2 + p3)) + ((p4 + p5) + (p6 + p7));
            uint4 pbu = uint4{pkbf(p0, p1), pkbf(p2, p3), pkbf(p4, p5), pkbf(p6, p7)};
            short8 pb; __builtin_memcpy(&pb, &pbu, 16);
            // single conflict-free b128 per operand: Vs columns are pre-permuted to k-slot order
            const short8 vf = *(const short8*)&Vs[grp][buf][q16][g * 32 + quad * 8];
            o0 = __builtin_amdgcn_mfma_f32_16x16x32_bf16(vf, pb, o0, 0, 0, 0);
            const short8 vb = *(const short8*)&Vs[grp][buf][16 + q16][g * 32 + quad * 8];
            o1 = __builtin_amdgcn_mfma_f32_16x16x32_bf16(vb, pb, o1, 0, 0, 0);
        }
        L += lsum;
    };

    // stage each group's tile 0
    *(uint4*)&Ks[grp][0][kr][kc * 8] = *(const uint4*)(kg);
    {
        uint2 va = *(const uint2*)(vg);
        uint2 vbr = *(const uint2*)(vg + 16);
        *(uint4*)&Vs[grp][0][vr][vc * 8] = uint4{va.x, va.y, vbr.x, vbr.y};
    }
    __syncthreads();

    for (int it = 0; it < 33; ++it) {       // 33 uniform barriers; group 0 idles at it=32
        const int buf = it & 1;
        uint4 kreg; uint2 vreg0, vreg1;
        const bool pre = (it + 1) < ntiles;
        if (pre) {
            kreg  = *(const uint4*)(kg + (size_t)(it + 1) * 2048);
            vreg0 = *(const uint2*)(vg + (it + 1) * 64);
            vreg1 = *(const uint2*)(vg + (it + 1) * 64 + 16);
        }
        if (it < ntiles) {
            if (grp == 0) tile(buf, oA0, oA1, LA);
            else if (it < 32) tile(buf, oA0, oA1, LA);   // tiles 32..63 (incl. pads)
            else              tile(buf, oB0, oB1, LB);   // tile 64 = mem segment
        }
        if (pre) {
            *(uint4*)&Ks[grp][buf ^ 1][kr][kc * 8] = kreg;
            *(uint4*)&Vs[grp][buf ^ 1][vr][vc * 8] = uint4{vreg0.x, vreg0.y, vreg1.x, vreg1.y};
        }
        __syncthreads();
    }

    LA += __shfl_xor(LA, 16); LA += __shfl_xor(LA, 32);
    LB += __shfl_xor(LB, 16); LB += __shfl_xor(LB, 32);

    // exchange group-0 partials through LDS (reuse Ks; all tile reads are done)
    float* ex = (float*)&Ks[0][0][0][0];    // [w4*64+lane]*12 : oA0[4], oA1[4], LA
    const int slot = (w4 * 64 + lane) * 12;
    if (grp == 0) {
        *(f32x4*)(ex + slot)     = oA0;
        *(f32x4*)(ex + slot + 4) = oA1;
        ex[slot + 8] = LA;
    }
    __syncthreads();

    if (grp == 1 && q < BN) {
        f32x4 a0 = *(const f32x4*)(ex + slot);
        f32x4 a1 = *(const f32x4*)(ex + slot + 4);
        float LT = LA + ex[slot + 8] - 48.f;     // 48 zero-pad keys contributed p=1 each
        const float iA = 1.f / LT, iB = 1.f / LB;
        const int b = bh >> 3, h = bh & 7;
        unsigned short* ap = AO + ((size_t)b * BN + q) * 256 + h * 32;
        float w0[4], w1[4];
        #pragma unroll
        for (int r = 0; r < 4; ++r) {
            w0[r] = (oA0[r] + a0[r]) * iA + oB0[r] * iB;   // hd = quad*4+r
            w1[r] = (oA1[r] + a1[r]) * iA + oB1[r] * iB;   // hd = 16+quad*4+r
        }
        *(uint2*)(ap + quad * 4)      = uint2{pkbf(w0[0], w0[1]), pkbf(w0[2], w0[3])};
        *(uint2*)(ap + 16 + quad * 4) = uint2{pkbf(w1[0], w1[1]), pkbf(w1[2], w1[3])};
    }
}

// ---------------- output GEMM ---------------- (unchanged)
__global__ __launch_bounds__(256)
void gemm_out(const unsigned short* __restrict__ A, const float* __restrict__ W,
              const float* __restrict__ bias, float* __restrict__ out)
{
    __shared__ __align__(16) short Ws[2][64][72];
    __shared__ __align__(16) short Ds[2][64][72];
    const int t    = threadIdx.x;
    const int wave = t >> 6, lane = t & 63, q16 = lane & 15, quad = lane >> 4;
    const int f0 = blockIdx.x * 64, m0 = blockIdx.y * 64;
    const int sr = t >> 2, sc = (t & 3) * 16;
    const int arow = m0 + sr;
    const bool aval = arow < MROWS;
    const float* wp = W + (size_t)(f0 + sr) * 256 + sc;
    const unsigned short* ap = A + (size_t)(aval ? arow : 0) * 256 + sc;

    f32x4 acc[4] = {{0,0,0,0},{0,0,0,0},{0,0,0,0},{0,0,0,0}};

    uint4 wr0, wr1, dr0, dr1;
    {
        float4 a0 = *(const float4*)(wp),     a1 = *(const float4*)(wp + 4);
        float4 a2 = *(const float4*)(wp + 8), a3 = *(const float4*)(wp + 12);
        wr0 = uint4{pkbf(a0.x,a0.y), pkbf(a0.z,a0.w), pkbf(a1.x,a1.y), pkbf(a1.z,a1.w)};
        wr1 = uint4{pkbf(a2.x,a2.y), pkbf(a2.z,a2.w), pkbf(a3.x,a3.y), pkbf(a3.z,a3.w)};
        dr0 = *(const uint4*)(ap); dr1 = *(const uint4*)(ap + 8);
    }
    *(uint4*)&Ws[0][sr][sc] = wr0; *(uint4*)&Ws[0][sr][sc + 8] = wr1;
    *(uint4*)&Ds[0][sr][sc] = dr0; *(uint4*)&Ds[0][sr][sc + 8] = dr1;
    __syncthreads();

    #pragma unroll
    for (int ki = 0; ki < 4; ++ki) {
        const int buf = ki & 1;
        if (ki < 3) {
            const int k1 = (ki + 1) * 64;
            float4 a0 = *(const float4*)(wp + k1),     a1 = *(const float4*)(wp + k1 + 4);
            float4 a2 = *(const float4*)(wp + k1 + 8), a3 = *(const float4*)(wp + k1 + 12);
            wr0 = uint4{pkbf(a0.x,a0.y), pkbf(a0.z,a0.w), pkbf(a1.x,a1.y), pkbf(a1.z,a1.w)};
            wr1 = uint4{pkbf(a2.x,a2.y), pkbf(a2.z,a2.w), pkbf(a3.x,a3.y), pkbf(a3.z,a3.w)};
            dr0 = *(const uint4*)(ap + k1); dr1 = *(const uint4*)(ap + k1 + 8);
        }
        #pragma unroll
        for (int ks = 0; ks < 2; ++ks) {
            const short8 af = *(const short8*)&Ws[buf][wave * 16 + q16][ks * 32 + quad * 8];
            #pragma unroll
            for (int ct = 0; ct < 4; ++ct) {
                const short8 bf = *(const short8*)&Ds[buf][ct * 16 + q16][ks * 32 + quad * 8];
                acc[ct] = __builtin_amdgcn_mfma_f32_16x16x32_bf16(af, bf, acc[ct], 0, 0, 0);
            }
        }
        if (ki < 3) {
            *(uint4*)&Ws[buf ^ 1][sr][sc] = wr0; *(uint4*)&Ws[buf ^ 1][sr][sc + 8] = wr1;
            *(uint4*)&Ds[buf ^ 1][sr][sc] = dr0; *(uint4*)&Ds[buf ^ 1][sr][sc + 8] = dr1;
            __syncthreads();
        }
    }

    const int fbase = f0 + wave * 16 + quad * 4;
    const float4 bb = *(const float4*)(bias + fbase);
    #pragma unroll
    for (int ct = 0; ct < 4; ++ct) {
        int n = m0 + ct * 16 + q16;
        if (n >= MROWS) continue;
        float* op = out + (size_t)n * 256 + fbase;
        *(float4*)op = float4{acc[ct][0] + bb.x, acc[ct][1] + bb.y,
                              acc[ct][2] + bb.z, acc[ct][3] + bb.w};
    }
}

extern "C" void kernel_launch(void* const* d_in, const int* in_sizes, int n_in,
                              void* d_out, int out_size, void* d_ws, size_t ws_size,
                              hipStream_t stream)
{
    (void)in_sizes; (void)n_in; (void)out_size; (void)ws_size;
    const float* q    = (const float*)d_in[0];
    const float* k    = (const float*)d_in[1];
    const float* v    = (const float*)d_in[2];
    const float* fimg = (const float*)d_in[3];
    const float* ftxt = (const float*)d_in[4];
    const float* Wq   = (const float*)d_in[5];
    const float* bq   = (const float*)d_in[6];
    const float* Wk   = (const float*)d_in[7];
    const float* bk   = (const float*)d_in[8];
    const float* Wv   = (const float*)d_in[9];
    const float* bv   = (const float*)d_in[10];
    const float* Wo   = (const float*)d_in[11];
    const float* bo   = (const float*)d_in[12];
    // d_in[13] = num_k_exclude_rope = 64 (compiled in)

    // workspace: Qr bf16 [16][BN][32]; Kr bf16 [16][NKR][32]; Vt bf16 [16][32][BNP];
    // AO bf16 [BB][BN][256]. Total 16,941,056 B (~16.2 MB)
    char* w = (char*)d_ws;
    short*          Qr = (short*)(w);                    //  4,210,688
    short*          Kr = (short*)(w + 4210688);          //  4,259,840
    short*          Vt = (short*)(w + 8470528);          //  4,259,840
    unsigned short* AO = (unsigned short*)(w + 12730368);//  4,210,688

    qkv_mfma<<<dim3(4, 129, 3), 256, 0, stream>>>(q, k, v, Wq, Wk, Wv, bq, bk, bv,
                                                  Qr, Kr, Vt, fimg, ftxt);
    attn_mfma<<<dim3(65, 16), 512, 0, stream>>>(Qr, Kr, Vt, AO);
    gemm_out<<<dim3(4, 129), 256, 0, stream>>>(AO, Wo, bo, (float*)d_out);
}